// Round 6
// baseline (91.588 us; speedup 1.0000x reference)
//
#include <hip/hip_runtime.h>

// ChamferLoss: B=4, N=M=8192, D=3, fp32. Scalar out.
// MFMA split-f16 (validated EXACT r6-r21): A = refs (LDS), B = queries (regs),
// in-lane min3 tree, VGPR-dest asm MFMA (r13).
// LEDGER: r0(2+2, 8-wave)=77.4 | r17 fence=149 | r18 presplit=80.1 |
// r19 presplit+gload_lds=82.8 | r20 4-fused @ 4-wave band=75.5 (BEST) |
// r21 rotated pipeline=77.4 (correct but slower).
// FACT: mfma kernel is ~28-31us across radically different schedules
// (schedule-INSENSITIVE) vs ~9-14us modeled floor - and it has NEVER
// appeared in rocprof top-5 (fills at ~41us occupy all slots). Six rounds
// of blind theory; three regressed. Buy the measurement.
// r22 DIAGNOSTIC (deliberately non-scoring): exact r20 kernel, gridDim.z=4,
// dir=z&1 -> each direction computed by two identical block-twins writing
// identical values (benign identical-value race, same class as out[0];
// absmax must stay 0.0). mfma dispatch ~56us -> top-1 in rocprof WITH
// MfmaUtil/VALUBusy/Occupancy/LDS_CONFLICT/FETCH/VGPR visible.
// Decision tree (committed): VALUBusy>=55 -> min3/tree-op cut; both<30 +
// occ~50% -> latency-bound, deepen pipeline or 8-wave band; occ~25% ->
// VGPR band wrong; LDS_CONFLICT big -> swizzle afrag; FETCH>>40MB ->
// input-read thrash. r23 reverts z=2 + applies the indicated fix.

#define BATCH   4
#define NPTS    8192
#define TPB     256
#define CSLICE  512                  // ref points per block (LDS slice)
#define QT      4                    // query tiles (32 cols) per wave
#define QBLK    (4 * QT * 32)        // 512 queries per block
#define MT      (CSLICE / 32)        // 16 ref tiles per slice
#define SLICES  (NPTS / CSLICE)      // 16
#define QBLKS   (NPTS / QBLK)        // 16

typedef _Float16 h8   __attribute__((ext_vector_type(8)));
typedef float    f16v __attribute__((ext_vector_type(16)));

__device__ __forceinline__ void split16(float v, _Float16& hi, _Float16& lo) {
    hi = (_Float16)v;
    lo = (_Float16)(v - (float)hi);
}

__device__ __forceinline__ float tree16(const f16v& d) {
    float g0 = fminf(fminf(d[0],  d[1]),  d[2]);
    float g1 = fminf(fminf(d[3],  d[4]),  d[5]);
    float g2 = fminf(fminf(d[6],  d[7]),  d[8]);
    float g3 = fminf(fminf(d[9],  d[10]), d[11]);
    float g4 = fminf(fminf(d[12], d[13]), d[14]);
    float h0 = fminf(fminf(g0, g1), d[15]);
    float h1 = fminf(fminf(g2, g3), g4);
    return fminf(h0, h1);
}

__global__ __launch_bounds__(TPB, 4) void chamfer_mfma(const float* __restrict__ xg,
                                                       const float* __restrict__ yg,
                                                       float* __restrict__ partial,
                                                       float* __restrict__ out) {
    __shared__ h8 afrag[CSLICE * 2];          // 16 KB, de-interleaved (conflict-free)

    const int tid    = threadIdx.x;
    const int qblock = blockIdx.x;            // [0,16)
    const int slice  = blockIdx.y & (SLICES - 1);
    const int b      = blockIdx.y >> 4;       // SLICES == 16
    const int dir    = blockIdx.z & 1;        // z in [0,4): twins per direction
    const int lane   = tid & 63, wave = tid >> 6;
    const int col    = lane & 31, hv = lane >> 5;

    if (tid == 0) out[0] = 0.0f;              // benign identical-value race;
                                              // reduce runs after via stream order
    const float* q = dir ? yg : xg;           // query side (cols, register B-frags)
    const float* r = dir ? xg : yg;           // reference side (rows, LDS A-frags)

    // ---- stage ref A-frags: 2 points per thread, de-interleaved layout ----
    const float* rbase = r + ((size_t)b * NPTS + slice * CSLICE) * 3;
#pragma unroll
    for (int i = 0; i < CSLICE / TPB; ++i) {
        const int p = tid + i * TPB;
        float r0 = rbase[p * 3 + 0], r1 = rbase[p * 3 + 1], r2 = rbase[p * 3 + 2];
        _Float16 h0, l0, h1, l1, h2, l2, rnh, rnl;
        split16(r0, h0, l0);                  // a-side: RAW coords
        split16(r1, h1, l1);
        split16(r2, h2, l2);
        split16(fmaf(r0, r0, fmaf(r1, r1, r2 * r2)), rnh, rnl);
        const int base = (p >> 5) * 64 + (p & 31);            // [tile][hv][row]
        afrag[base]      = (h8){h0, h1, h2, l0, l1, l2, h0, h1};            // k0..7
        afrag[base + 32] = (h8){h2, rnh, rnl, (_Float16)1.0f, (_Float16)1.0f,
                                (_Float16)0.0f, (_Float16)0.0f, (_Float16)0.0f}; // k8..15
    }

    // ---- query B-frags: QT col-tiles per wave, resident in registers ----
    h8 bq[QT];
#pragma unroll
    for (int t = 0; t < QT; ++t) {
        const int qi = qblock * QBLK + (wave * QT + t) * 32 + col;
        const float* qp = q + ((size_t)b * NPTS + qi) * 3;
        float x0 = qp[0], x1 = qp[1], x2 = qp[2];
        _Float16 H0, L0, H1, L1, H2, L2, qnh, qnl;
        split16(-2.0f * x0, H0, L0);          // b-side: -2q, split AFTER scaling
        split16(-2.0f * x1, H1, L1);
        split16(-2.0f * x2, H2, L2);
        split16(fmaf(x0, x0, fmaf(x1, x1, x2 * x2)), qnh, qnl);
        h8 b0 = {H0, H1, H2, H0, H1, H2, L0, L1};                           // k0..7
        h8 b1 = {L2, (_Float16)1.0f, (_Float16)1.0f, qnh, qnl,
                 (_Float16)0.0f, (_Float16)0.0f, (_Float16)0.0f};           // k8..15
        bq[t] = hv ? b1 : b0;
    }
    __syncthreads();

    float cm[QT];
#pragma unroll
    for (int t = 0; t < QT; ++t) cm[t] = 3.0e38f;

    // ---- main loop: 1 A-frag read -> 4 MFMAs back-to-back, then 4 trees ----
    for (int mt = 0; mt < MT; ++mt) {
        const h8 ar = afrag[mt * 64 + lane];   // contiguous 16B/lane, conflict-free
        f16v d0, d1, d2, d3;
        asm("v_mfma_f32_32x32x16_f16 %0, %4, %5, 0\n\t"
            "v_mfma_f32_32x32x16_f16 %1, %4, %6, 0\n\t"
            "v_mfma_f32_32x32x16_f16 %2, %4, %7, 0\n\t"
            "v_mfma_f32_32x32x16_f16 %3, %4, %8, 0\n\t"
            "s_nop 7\n\t"
            "s_nop 7"
            : "=v"(d0), "=v"(d1), "=v"(d2), "=v"(d3)
            : "v"(ar), "v"(bq[0]), "v"(bq[1]), "v"(bq[2]), "v"(bq[3]));
        cm[0] = fminf(cm[0], tree16(d0));
        cm[1] = fminf(cm[1], tree16(d1));
        cm[2] = fminf(cm[2], tree16(d2));
        cm[3] = fminf(cm[3], tree16(d3));
    }

    // ---- epilogue: one xor32 per accumulator, coalesced stores ----
    // z-twins write identical values to identical addresses: benign.
    float* pp = partial + ((size_t)(dir * BATCH + b) * SLICES + slice) * NPTS
                        + qblock * QBLK;
#pragma unroll
    for (int t = 0; t < QT; ++t) {
        cm[t] = fminf(cm[t], __shfl_xor(cm[t], 32, 64));   // hv-partner rows
        if (hv == 0)
            pp[(wave * QT + t) * 32 + col] = cm[t];        // 32 lanes, 128B coalesced
    }
}

__global__ __launch_bounds__(TPB) void chamfer_reduce(const float* __restrict__ partial,
                                                      float* __restrict__ out) {
    const int tid = threadIdx.x;
    const int g   = blockIdx.x * TPB + tid;   // [0, 2*BATCH*NPTS)
    const int db  = g >> 13;                  // (dir*BATCH + b)
    const int n   = g & (NPTS - 1);

    const float* p = partial + (size_t)db * SLICES * NPTS + n;
    float v = 3.0e38f;
#pragma unroll
    for (int s = 0; s < SLICES; ++s)
        v = fminf(v, p[(size_t)s * NPTS]);    // coalesced across threads

    float w = v;
#pragma unroll
    for (int off = 32; off > 0; off >>= 1)
        w += __shfl_down(w, off, 64);
    __shared__ float ss[TPB / 64];
    if ((tid & 63) == 0) ss[tid >> 6] = w;
    __syncthreads();
    if (tid == 0)
        atomicAdd(out, (ss[0] + ss[1] + ss[2] + ss[3]) * (1.0f / (float)(BATCH * NPTS)));
}

extern "C" void kernel_launch(void* const* d_in, const int* in_sizes, int n_in,
                              void* d_out, int out_size, void* d_ws, size_t ws_size,
                              hipStream_t stream) {
    const float* x = (const float*)d_in[0];
    const float* y = (const float*)d_in[1];
    float* out = (float*)d_out;
    float* partial = (float*)d_ws;            // 2*4*16*8192*4 = 4 MB

    // DIAGNOSTIC: z=4 (two identical twins per direction) to push chamfer_mfma
    // into rocprof top-5 with counters. r23 reverts to z=2.
    chamfer_mfma<<<dim3(QBLKS, BATCH * SLICES, 4), TPB, 0, stream>>>(x, y, partial, out);
    chamfer_reduce<<<dim3(2 * BATCH * NPTS / TPB), TPB, 0, stream>>>(partial, out);
}

// Round 7
// 75.938 us; speedup vs baseline: 1.2061x; 1.2061x over previous
//
#include <hip/hip_runtime.h>

// ChamferLoss: B=4, N=M=8192, D=3, fp32. Scalar out.
// MFMA split-f16 (validated EXACT r6-r22): A = refs (LDS), B = queries (regs),
// in-lane min3 tree, VGPR-dest asm MFMA (r13), 4-fused issue group @ 4-wave
// band (r20).
// LEDGER: r0(2+2, 8-wave)=77.4 | r17 fence=149 | r18 presplit=80.1 |
// r19 presplit+gload_lds=82.8 | r20 4-fused @ (256,4)=75.5 (BEST) |
// r21 rotated pipeline=77.4 | r22 z=4 diagnostic=91.6.
// r22 MEASUREMENT: dur(z4)-dur(z2)=16.1us => chamfer_mfma ~= 16us (not 28).
// Fill(s)+gaps ~= 56us FIXED. Revised pipe model per CU (8 blk history):
// MFMA 6.9us, tree VALU 6.4us, prologue VALU 4.5us (170 instr/thread:
// staging 50 + B-frag 120, redundant 16x across slice-blocks). Kernel is
// VALU-throughput-bound -> explains r20/r21 schedule-insensitivity.
// r23 (this): SPASS=2, single delta vs r20. Each block stages 1024 refs
// (2 slices, 32KB LDS) and runs one 32-tile loop with the SAME bq ->
// blocks 2048->1024 (exactly 4/CU), total B-frag VALU halved, barriers/
// epilogues halved, partial 16->8 rows (reduce reads halved). A-staging
// total unchanged. Inner loop/asm/band identical to r20.
// Guards: absmax!=0 -> revert r20. Flat timing -> prologue share wrong;
// run z=8 diagnostic (mfma ~64us > fills -> counters visible) next.

#define BATCH   4
#define NPTS    8192
#define TPB     256
#define SPAN    1024                 // ref points per block (2 old slices)
#define QT      4                    // query tiles (32 cols) per wave
#define QBLK    (4 * QT * 32)        // 512 queries per block
#define MT2     (SPAN / 32)          // 32 ref tiles per block
#define SROWS   (NPTS / SPAN)        // 8 partial rows per (dir,b)
#define QBLKS   (NPTS / QBLK)        // 16

typedef _Float16 h8   __attribute__((ext_vector_type(8)));
typedef float    f16v __attribute__((ext_vector_type(16)));

__device__ __forceinline__ void split16(float v, _Float16& hi, _Float16& lo) {
    hi = (_Float16)v;
    lo = (_Float16)(v - (float)hi);
}

__device__ __forceinline__ float tree16(const f16v& d) {
    float g0 = fminf(fminf(d[0],  d[1]),  d[2]);
    float g1 = fminf(fminf(d[3],  d[4]),  d[5]);
    float g2 = fminf(fminf(d[6],  d[7]),  d[8]);
    float g3 = fminf(fminf(d[9],  d[10]), d[11]);
    float g4 = fminf(fminf(d[12], d[13]), d[14]);
    float h0 = fminf(fminf(g0, g1), d[15]);
    float h1 = fminf(fminf(g2, g3), g4);
    return fminf(h0, h1);
}

__global__ __launch_bounds__(TPB, 4) void chamfer_mfma(const float* __restrict__ xg,
                                                       const float* __restrict__ yg,
                                                       float* __restrict__ partial,
                                                       float* __restrict__ out) {
    __shared__ h8 afrag[SPAN * 2];            // 32 KB, de-interleaved (conflict-free)

    const int tid    = threadIdx.x;
    const int qblock = blockIdx.x;            // [0,16)
    const int sp     = blockIdx.y & (SROWS - 1);   // slice-pair [0,8)
    const int b      = blockIdx.y >> 3;       // SROWS == 8
    const int dir    = blockIdx.z;
    const int lane   = tid & 63, wave = tid >> 6;
    const int col    = lane & 31, hv = lane >> 5;

    if (tid == 0) out[0] = 0.0f;              // benign identical-value race;
                                              // reduce runs after via stream order
    const float* q = dir ? yg : xg;           // query side (cols, register B-frags)
    const float* r = dir ? xg : yg;           // reference side (rows, LDS A-frags)

    // ---- stage ref A-frags: 4 points per thread, de-interleaved layout ----
    const float* rbase = r + ((size_t)b * NPTS + sp * SPAN) * 3;
#pragma unroll
    for (int i = 0; i < SPAN / TPB; ++i) {
        const int p = tid + i * TPB;
        float r0 = rbase[p * 3 + 0], r1 = rbase[p * 3 + 1], r2 = rbase[p * 3 + 2];
        _Float16 h0, l0, h1, l1, h2, l2, rnh, rnl;
        split16(r0, h0, l0);                  // a-side: RAW coords
        split16(r1, h1, l1);
        split16(r2, h2, l2);
        split16(fmaf(r0, r0, fmaf(r1, r1, r2 * r2)), rnh, rnl);
        const int base = (p >> 5) * 64 + (p & 31);            // [tile][hv][row]
        afrag[base]      = (h8){h0, h1, h2, l0, l1, l2, h0, h1};            // k0..7
        afrag[base + 32] = (h8){h2, rnh, rnl, (_Float16)1.0f, (_Float16)1.0f,
                                (_Float16)0.0f, (_Float16)0.0f, (_Float16)0.0f}; // k8..15
    }

    // ---- query B-frags: QT col-tiles per wave, resident in registers ----
    h8 bq[QT];
#pragma unroll
    for (int t = 0; t < QT; ++t) {
        const int qi = qblock * QBLK + (wave * QT + t) * 32 + col;
        const float* qp = q + ((size_t)b * NPTS + qi) * 3;
        float x0 = qp[0], x1 = qp[1], x2 = qp[2];
        _Float16 H0, L0, H1, L1, H2, L2, qnh, qnl;
        split16(-2.0f * x0, H0, L0);          // b-side: -2q, split AFTER scaling
        split16(-2.0f * x1, H1, L1);
        split16(-2.0f * x2, H2, L2);
        split16(fmaf(x0, x0, fmaf(x1, x1, x2 * x2)), qnh, qnl);
        h8 b0 = {H0, H1, H2, H0, H1, H2, L0, L1};                           // k0..7
        h8 b1 = {L2, (_Float16)1.0f, (_Float16)1.0f, qnh, qnl,
                 (_Float16)0.0f, (_Float16)0.0f, (_Float16)0.0f};           // k8..15
        bq[t] = hv ? b1 : b0;
    }
    __syncthreads();

    float cm[QT];
#pragma unroll
    for (int t = 0; t < QT; ++t) cm[t] = 3.0e38f;

    // ---- main loop: 32 tiles; 1 A-frag read -> 4 MFMAs back-to-back, 4 trees ----
    for (int mt = 0; mt < MT2; ++mt) {
        const h8 ar = afrag[mt * 64 + lane];   // contiguous 16B/lane, conflict-free
        f16v d0, d1, d2, d3;
        asm("v_mfma_f32_32x32x16_f16 %0, %4, %5, 0\n\t"
            "v_mfma_f32_32x32x16_f16 %1, %4, %6, 0\n\t"
            "v_mfma_f32_32x32x16_f16 %2, %4, %7, 0\n\t"
            "v_mfma_f32_32x32x16_f16 %3, %4, %8, 0\n\t"
            "s_nop 7\n\t"
            "s_nop 7"
            : "=v"(d0), "=v"(d1), "=v"(d2), "=v"(d3)
            : "v"(ar), "v"(bq[0]), "v"(bq[1]), "v"(bq[2]), "v"(bq[3]));
        cm[0] = fminf(cm[0], tree16(d0));
        cm[1] = fminf(cm[1], tree16(d1));
        cm[2] = fminf(cm[2], tree16(d2));
        cm[3] = fminf(cm[3], tree16(d3));
    }

    // ---- epilogue: one xor32 per accumulator, coalesced stores ----
    float* pp = partial + ((size_t)(dir * BATCH + b) * SROWS + sp) * NPTS
                        + qblock * QBLK;
#pragma unroll
    for (int t = 0; t < QT; ++t) {
        cm[t] = fminf(cm[t], __shfl_xor(cm[t], 32, 64));   // hv-partner rows
        if (hv == 0)
            pp[(wave * QT + t) * 32 + col] = cm[t];        // 32 lanes, 128B coalesced
    }
}

__global__ __launch_bounds__(TPB) void chamfer_reduce(const float* __restrict__ partial,
                                                      float* __restrict__ out) {
    const int tid = threadIdx.x;
    const int g   = blockIdx.x * TPB + tid;   // [0, 2*BATCH*NPTS)
    const int db  = g >> 13;                  // (dir*BATCH + b)
    const int n   = g & (NPTS - 1);

    const float* p = partial + (size_t)db * SROWS * NPTS + n;
    float v = 3.0e38f;
#pragma unroll
    for (int s = 0; s < SROWS; ++s)
        v = fminf(v, p[(size_t)s * NPTS]);    // coalesced across threads

    float w = v;
#pragma unroll
    for (int off = 32; off > 0; off >>= 1)
        w += __shfl_down(w, off, 64);
    __shared__ float ss[TPB / 64];
    if ((tid & 63) == 0) ss[tid >> 6] = w;
    __syncthreads();
    if (tid == 0)
        atomicAdd(out, (ss[0] + ss[1] + ss[2] + ss[3]) * (1.0f / (float)(BATCH * NPTS)));
}

extern "C" void kernel_launch(void* const* d_in, const int* in_sizes, int n_in,
                              void* d_out, int out_size, void* d_ws, size_t ws_size,
                              hipStream_t stream) {
    const float* x = (const float*)d_in[0];
    const float* y = (const float*)d_in[1];
    float* out = (float*)d_out;
    float* partial = (float*)d_ws;            // 2*4*8*8192*4 = 2 MB

    chamfer_mfma<<<dim3(QBLKS, BATCH * SROWS, 2), TPB, 0, stream>>>(x, y, partial, out);
    chamfer_reduce<<<dim3(2 * BATCH * NPTS / TPB), TPB, 0, stream>>>(partial, out);
}